// Round 9
// baseline (197.757 us; speedup 1.0000x reference)
//
#include <hip/hip_runtime.h>
#include <hip/hip_bf16.h>

#define N_NODES 40000
#define N_EDGES 640000
#define DIM     128
#define NB      157    // scan blocks (256 threads)
#define GEMMB   625    // gemm blocks (64 rows each)
#define HEB     1250   // scatter blocks (2 edges/thread)
#define CHUNKS  64     // hist chunks (one block each)
#define CHUNK_E 10000  // edges per chunk
#define LDSW    10000  // u32 words packing 40000 u8 counters

#define HIST0   65     // first hist block in D1

typedef __attribute__((ext_vector_type(8))) short short8;
typedef __attribute__((ext_vector_type(4))) float f32x4;
typedef __attribute__((ext_vector_type(2))) float f32x2;

__device__ inline short f2bf(float f) {
    __hip_bfloat16 h = __float2bfloat16(f);
    return *reinterpret_cast<short*>(&h);
}
__device__ inline float bf2f(short u) {
    union { unsigned int i; float f; } x;
    x.i = ((unsigned int)(unsigned short)u) << 16;
    return x.f;
}

// fragment-order index for element (k,n) of a 128x128 W, matching the
// MFMA B-fragment read: lane l reads slot (kb*8+nt)*64 + l as short8.
__device__ inline int fragidx(int k, int n) {
    int kb = k >> 5, kq = (k >> 3) & 3, j = k & 7;
    int nt = n >> 4, nl = n & 15;
    return (((kb * 8 + nt) * 64 + kq * 16 + nl) * 8 + j);
}

// ---------------------------------------------------------------------------
// D1: blocks [0,64) weight prep; block 64 zeros flags+totals;
// blocks [65,129) LDS chunk histograms (hist needs only `rows`).
// ---------------------------------------------------------------------------
__global__ __launch_bounds__(256) void prep_hist_zero(const float* __restrict__ Wt,
                                                      const float* __restrict__ W0,
                                                      const float* __restrict__ W1,
                                                      const float* __restrict__ bt,
                                                      short* __restrict__ WtF,
                                                      short* __restrict__ WfF,
                                                      short* __restrict__ W1F,
                                                      float* __restrict__ btf,
                                                      int* __restrict__ flagtot,
                                                      const int* __restrict__ rows,
                                                      unsigned char* __restrict__ rank8,
                                                      unsigned int* __restrict__ cnt8w) {
    __shared__ unsigned int lcnt[LDSW];   // 40 KB (hist blocks only)
    const int b = blockIdx.x;

    if (b < 64) {
        int gid = b * 256 + threadIdx.x;            // 0..16383
        int k = gid >> 7, n = gid & 127;
        float wf = 0.f;
        for (int kk = 0; kk < 128; ++kk)
            wf += Wt[k * 128 + kk] * W0[kk * 128 + n];
        int fi = fragidx(k, n);
        WtF[fi] = f2bf(Wt[k * 128 + n]);
        W1F[fi] = f2bf(W1[k * 128 + n]);
        WfF[fi] = f2bf(wf);
        if (gid < 128) {
            float s = 0.f;
            for (int kk = 0; kk < 128; ++kk) s += bt[kk] * W0[kk * 128 + n];
            btf[n] = s;
        }
    } else if (b == 64) {
        flagtot[threadIdx.x]       = 0;   // flags
        flagtot[threadIdx.x + 256] = 0;   // totals
    } else {
        // LDS histogram of one 10000-edge chunk: u8 counters packed 4/u32;
        // returning LDS atomicAdd gives rank within chunk-bucket.
        for (int i = threadIdx.x; i < LDSW; i += 256) lcnt[i] = 0u;
        __syncthreads();
        const int base = (b - HIST0) * CHUNK_E;
#pragma unroll
        for (int i = 0; i < 40; ++i) {
            int o = i * 256 + threadIdx.x;
            if (o < CHUNK_E) {
                int e = base + o;
                int r = rows[e];
                unsigned int sh = (unsigned int)(r & 3) * 8u;
                unsigned int old = atomicAdd(&lcnt[r >> 2], 1u << sh);
                rank8[e] = (unsigned char)((old >> sh) & 0xFFu);
            }
        }
        __syncthreads();
        unsigned int* out = cnt8w + (size_t)(b - HIST0) * LDSW;
        for (int i = threadIdx.x; i < LDSW; i += 256) out[i] = lcnt[i];
    }
}

// ---------------------------------------------------------------------------
// D2: single-pass scan (standalone dispatch — publish-then-spin is only safe
// when these 157 blocks are alone on the machine; R1 proved that).
// ---------------------------------------------------------------------------
__global__ __launch_bounds__(256) void scan_onepass(unsigned char* __restrict__ cnt8,
                                                    int* __restrict__ flags,
                                                    int* __restrict__ totals,
                                                    int* __restrict__ row_ptr) {
    __shared__ int sh[256];
    const int b = blockIdx.x;
    const int t = threadIdx.x;
    const int i = b * 256 + t;

    int deg = 0;
    if (i < N_NODES) {
#pragma unroll 8
        for (int c = 0; c < CHUNKS; ++c) deg += cnt8[(size_t)c * N_NODES + i];
    }

    int val = deg;
    sh[t] = val;
    __syncthreads();
    for (int off = 1; off < 256; off <<= 1) {
        int a = (t >= off) ? sh[t - off] : 0;
        __syncthreads();
        val += a;
        sh[t] = val;
        __syncthreads();
    }
    const int excl  = val - deg;
    const int total = sh[255];

    if (t == 0) {
        atomicExch(&totals[b], total);
        __threadfence();
        atomicExch(&flags[b], 1);
    }

    int v = 0;
    if (t < NB) {
        while (atomicAdd(&flags[t], 0) == 0) { }
        v = atomicAdd(&totals[t], 0);
    }
    __syncthreads();
    int val2 = v;
    sh[t] = val2;
    __syncthreads();
    for (int off = 1; off < 256; off <<= 1) {
        int a = (t >= off) ? sh[t - off] : 0;
        __syncthreads();
        val2 += a;
        sh[t] = val2;
        __syncthreads();
    }
    int blkOff = (b == 0) ? 0 : sh[b - 1];

    if (i < N_NODES) {
        int base = excl + blkOff;
        row_ptr[i] = base;
        int run = 0;
#pragma unroll 8
        for (int c = 0; c < CHUNKS; ++c) {
            int cv = cnt8[(size_t)c * N_NODES + i];
            cnt8[(size_t)c * N_NODES + i] = (unsigned char)run;
            run += cv;
        }
    }
    if (i == 0) row_ptr[N_NODES] = N_EDGES;
}

// ---------------------------------------------------------------------------
// D3: dual GEMM || scatter fused — ZERO intra-dispatch dependency.
//   blocks [0,625):      H = x@Wt + bt (fp32, NT store), Z0 = bf16(...)
//   blocks [625,1875):   scatter: pos = row_ptr[r] + pref8[chunk][r] + rank8[e]
// Streaming traffic (A reads, H stores, rows/cols reads) is nontemporal so
// L2 keeps capacity for the reused gather data (Z0, adj, pref8).
// ---------------------------------------------------------------------------
__global__ __launch_bounds__(256) void gemm_scatter(const float* __restrict__ A,
                                                    const short* __restrict__ WtF,
                                                    const short* __restrict__ WfF,
                                                    const float* __restrict__ bt,
                                                    const float* __restrict__ btf,
                                                    float* __restrict__ H,
                                                    __hip_bfloat16* __restrict__ Z,
                                                    const int* __restrict__ rows,
                                                    const int* __restrict__ cols,
                                                    const unsigned char* __restrict__ rank8,
                                                    const unsigned char* __restrict__ pref8,
                                                    const int* __restrict__ row_ptr,
                                                    unsigned short* __restrict__ adj) {
    const int blk = blockIdx.x;
    const int t   = threadIdx.x;

    if (blk < GEMMB) {
        // ---------------- dual-GEMM role ----------------
        const int wave = t >> 6;
        const int l    = t & 63;
        const int nl   = l & 15;
        const int quad = l >> 4;
        const int wRow = blk * 64 + wave * 16;

        f32x4 accH[8], accZ[8];
#pragma unroll
        for (int nt = 0; nt < 8; ++nt) {
            accH[nt] = (f32x4){0.f, 0.f, 0.f, 0.f};
            accZ[nt] = (f32x4){0.f, 0.f, 0.f, 0.f};
        }

#pragma unroll
        for (int kb = 0; kb < 4; ++kb) {
            const float* ap = A + (size_t)(wRow + nl) * 128 + kb * 32 + quad * 8;
            f32x4 f0 = __builtin_nontemporal_load((const f32x4*)ap);
            f32x4 f1 = __builtin_nontemporal_load((const f32x4*)(ap + 4));
            short8 afrag;
            afrag[0] = f2bf(f0.x); afrag[1] = f2bf(f0.y);
            afrag[2] = f2bf(f0.z); afrag[3] = f2bf(f0.w);
            afrag[4] = f2bf(f1.x); afrag[5] = f2bf(f1.y);
            afrag[6] = f2bf(f1.z); afrag[7] = f2bf(f1.w);
#pragma unroll
            for (int nt = 0; nt < 8; ++nt) {
                int off = ((kb * 8 + nt) * 64 + l) * 8;
                short8 bt_frag = *(const short8*)&WtF[off];
                short8 bf_frag = *(const short8*)&WfF[off];
                accH[nt] = __builtin_amdgcn_mfma_f32_16x16x32_bf16(afrag, bt_frag, accH[nt], 0, 0, 0);
                accZ[nt] = __builtin_amdgcn_mfma_f32_16x16x32_bf16(afrag, bf_frag, accZ[nt], 0, 0, 0);
            }
        }

#pragma unroll
        for (int nt = 0; nt < 8; ++nt) {
            int col = nt * 16 + nl;
            float bH = bt[col];
            float bZ = btf[col];
#pragma unroll
            for (int r = 0; r < 4; ++r) {
                int row = wRow + quad * 4 + r;
                __builtin_nontemporal_store(accH[nt][r] + bH, &H[(size_t)row * 128 + col]);
                *(short*)&Z[(size_t)row * 128 + col] = f2bf(accZ[nt][r] + bZ);
            }
        }
        return;
    }

    // ---------------- scatter role (atomic-free) ----------------
    int gid = (blk - GEMMB) * 256 + t;            // 0..319999
#pragma unroll
    for (int h = 0; h < 2; ++h) {
        int e = gid + h * HEB * 256;
        int r = __builtin_nontemporal_load(&rows[e]);
        int c = e / CHUNK_E;
        int pos = row_ptr[r] + (int)pref8[(size_t)c * N_NODES + r] + (int)rank8[e];
        adj[pos] = (unsigned short)__builtin_nontemporal_load(&cols[e]);
    }
}

// ---------------------------------------------------------------------------
// D4: fused layer-0 agg + layer-1 GEMM — quad-per-node bf16 gather (natural
// order; R5/R6 proved degree-sort loses to locality). 8/4/2/1 unroll ladder
// keeps up to 8 rows in flight per quad. H read/write nontemporal (streamed
// once) so L2 keeps the 10 MB Z0 gather set hot.
// ---------------------------------------------------------------------------
__global__ __launch_bounds__(256) void agg0_gemm(const __hip_bfloat16* __restrict__ z0,
                                                 const int* __restrict__ row_ptr,
                                                 const unsigned short* __restrict__ adj,
                                                 const float* __restrict__ bias,
                                                 const short* __restrict__ W1F,
                                                 float* __restrict__ H,
                                                 unsigned char* __restrict__ Z1) {
    __shared__ short hs[16][136];   // +8 shorts pad

    const int t    = threadIdx.x;
    const int wave = t >> 6;
    const int l    = t & 63;
    const int quad = l >> 4;
    const int sl   = l & 15;
    const int nodeBase = blockIdx.x * 16;
    const int m    = wave * 4 + quad;      // 0..15, this quad's node slot
    const int node = nodeBase + m;

    const int s = row_ptr[node];
    const int e = row_ptr[node + 1];

    float acc[8];
#pragma unroll
    for (int j = 0; j < 8; ++j) acc[j] = 0.f;

    const __hip_bfloat16* zb = z0 + sl * 8;
    int it = s;
    for (; it + 7 < e; it += 8) {
        int c0 = adj[it + 0], c1 = adj[it + 1], c2 = adj[it + 2], c3 = adj[it + 3];
        int c4 = adj[it + 4], c5 = adj[it + 5], c6 = adj[it + 6], c7 = adj[it + 7];
        short8 v0 = *(const short8*)&zb[(size_t)c0 * DIM];
        short8 v1 = *(const short8*)&zb[(size_t)c1 * DIM];
        short8 v2 = *(const short8*)&zb[(size_t)c2 * DIM];
        short8 v3 = *(const short8*)&zb[(size_t)c3 * DIM];
        short8 v4 = *(const short8*)&zb[(size_t)c4 * DIM];
        short8 v5 = *(const short8*)&zb[(size_t)c5 * DIM];
        short8 v6 = *(const short8*)&zb[(size_t)c6 * DIM];
        short8 v7 = *(const short8*)&zb[(size_t)c7 * DIM];
#pragma unroll
        for (int j = 0; j < 8; ++j)
            acc[j] += ((bf2f(v0[j]) + bf2f(v1[j])) + (bf2f(v2[j]) + bf2f(v3[j]))) +
                      ((bf2f(v4[j]) + bf2f(v5[j])) + (bf2f(v6[j]) + bf2f(v7[j])));
    }
    for (; it + 3 < e; it += 4) {
        int c0 = adj[it + 0], c1 = adj[it + 1], c2 = adj[it + 2], c3 = adj[it + 3];
        short8 v0 = *(const short8*)&zb[(size_t)c0 * DIM];
        short8 v1 = *(const short8*)&zb[(size_t)c1 * DIM];
        short8 v2 = *(const short8*)&zb[(size_t)c2 * DIM];
        short8 v3 = *(const short8*)&zb[(size_t)c3 * DIM];
#pragma unroll
        for (int j = 0; j < 8; ++j)
            acc[j] += (bf2f(v0[j]) + bf2f(v1[j])) + (bf2f(v2[j]) + bf2f(v3[j]));
    }
    for (; it + 1 < e; it += 2) {
        int c0 = adj[it + 0], c1 = adj[it + 1];
        short8 v0 = *(const short8*)&zb[(size_t)c0 * DIM];
        short8 v1 = *(const short8*)&zb[(size_t)c1 * DIM];
#pragma unroll
        for (int j = 0; j < 8; ++j) acc[j] += bf2f(v0[j]) + bf2f(v1[j]);
    }
    if (it < e) {
        int c = adj[it];
        short8 v = *(const short8*)&zb[(size_t)c * DIM];
#pragma unroll
        for (int j = 0; j < 8; ++j) acc[j] += bf2f(v[j]);
    }

    // residual update (each quad owns its node; all 16 lanes write 8 floats)
    {
        float* hp = H + (size_t)node * DIM + sl * 8;
        f32x4 h0 = __builtin_nontemporal_load((const f32x4*)hp);
        f32x4 h1 = __builtin_nontemporal_load((const f32x4*)(hp + 4));
        float4 b0v = *(const float4*)&bias[sl * 8];
        float4 b1v = *(const float4*)&bias[sl * 8 + 4];
        float r[8];
        r[0] = acc[0] + b0v.x; r[1] = acc[1] + b0v.y; r[2] = acc[2] + b0v.z; r[3] = acc[3] + b0v.w;
        r[4] = acc[4] + b1v.x; r[5] = acc[5] + b1v.y; r[6] = acc[6] + b1v.z; r[7] = acc[7] + b1v.w;
        float hn[8];
        hn[0] = h0.x; hn[1] = h0.y; hn[2] = h0.z; hn[3] = h0.w;
        hn[4] = h1.x; hn[5] = h1.y; hn[6] = h1.z; hn[7] = h1.w;
        short8 o;
#pragma unroll
        for (int j = 0; j < 8; ++j) {
            float rr = r[j] > 0.f ? r[j] : 0.f;
            hn[j] += rr;
            o[j] = f2bf(hn[j]);
        }
        f32x4 s0 = (f32x4){hn[0], hn[1], hn[2], hn[3]};
        f32x4 s1 = (f32x4){hn[4], hn[5], hn[6], hn[7]};
        __builtin_nontemporal_store(s0, (f32x4*)hp);
        __builtin_nontemporal_store(s1, (f32x4*)(hp + 4));
        *(short8*)&hs[m][sl * 8] = o;
    }
    __syncthreads();

    // phase 2: Z1[16x128] = hs @ W1 ; wave handles cols [wave*32, wave*32+32)
    f32x4 acc2[2];
    acc2[0] = (f32x4){0.f, 0.f, 0.f, 0.f};
    acc2[1] = (f32x4){0.f, 0.f, 0.f, 0.f};
#pragma unroll
    for (int kb = 0; kb < 4; ++kb) {
        short8 afrag = *(const short8*)&hs[sl][kb * 32 + quad * 8];
#pragma unroll
        for (int nt2 = 0; nt2 < 2; ++nt2) {
            int nt = wave * 2 + nt2;
            short8 bfrag = *(const short8*)&W1F[((kb * 8 + nt) * 64 + l) * 8];
            acc2[nt2] = __builtin_amdgcn_mfma_f32_16x16x32_bf16(afrag, bfrag, acc2[nt2], 0, 0, 0);
        }
    }
#pragma unroll
    for (int nt2 = 0; nt2 < 2; ++nt2) {
        int col = (wave * 2 + nt2) * 16 + sl;
#pragma unroll
        for (int r = 0; r < 4; ++r) {
            int row = nodeBase + quad * 4 + r;
            float v = acc2[nt2][r];
            int packed = __builtin_amdgcn_cvt_pk_fp8_f32(v, v, 0, false);
            Z1[(size_t)row * 128 + col] = (unsigned char)(packed & 0xFF);
        }
    }
}

// ---------------------------------------------------------------------------
// D5: final aggregation over fp8 Z1 — quad-per-node gather (16 nodes/block,
// natural order). H read/write nontemporal. H[node] += relu(agg(Z1)+b1).
// ---------------------------------------------------------------------------
__global__ __launch_bounds__(256) void agg_final(const unsigned char* __restrict__ z1,
                                                 const int* __restrict__ row_ptr,
                                                 const unsigned short* __restrict__ adj,
                                                 const float* __restrict__ bias,
                                                 float* __restrict__ H) {
    const int t    = threadIdx.x;
    const int wave = t >> 6;
    const int l    = t & 63;
    const int quad = l >> 4;
    const int sl   = l & 15;
    const int node = blockIdx.x * 16 + wave * 4 + quad;
    if (node >= N_NODES) return;

    const int s = row_ptr[node];
    const int e = row_ptr[node + 1];

    float acc[8];
#pragma unroll
    for (int j = 0; j < 8; ++j) acc[j] = 0.f;

#define ADD_FP8(u2)                                                          \
    {                                                                        \
        f32x2 a0 = __builtin_amdgcn_cvt_pk_f32_fp8((u2).x, false);           \
        f32x2 a1 = __builtin_amdgcn_cvt_pk_f32_fp8((u2).x, true);            \
        f32x2 a2 = __builtin_amdgcn_cvt_pk_f32_fp8((u2).y, false);           \
        f32x2 a3 = __builtin_amdgcn_cvt_pk_f32_fp8((u2).y, true);            \
        acc[0] += a0.x; acc[1] += a0.y; acc[2] += a1.x; acc[3] += a1.y;      \
        acc[4] += a2.x; acc[5] += a2.y; acc[6] += a3.x; acc[7] += a3.y;      \
    }

    const unsigned char* zb = z1 + sl * 8;
    int it = s;
    for (; it + 7 < e; it += 8) {
        int c0 = adj[it + 0], c1 = adj[it + 1], c2 = adj[it + 2], c3 = adj[it + 3];
        int c4 = adj[it + 4], c5 = adj[it + 5], c6 = adj[it + 6], c7 = adj[it + 7];
        uint2 v0 = *(const uint2*)&zb[(size_t)c0 * 128];
        uint2 v1 = *(const uint2*)&zb[(size_t)c1 * 128];
        uint2 v2 = *(const uint2*)&zb[(size_t)c2 * 128];
        uint2 v3 = *(const uint2*)&zb[(size_t)c3 * 128];
        uint2 v4 = *(const uint2*)&zb[(size_t)c4 * 128];
        uint2 v5 = *(const uint2*)&zb[(size_t)c5 * 128];
        uint2 v6 = *(const uint2*)&zb[(size_t)c6 * 128];
        uint2 v7 = *(const uint2*)&zb[(size_t)c7 * 128];
        ADD_FP8(v0); ADD_FP8(v1); ADD_FP8(v2); ADD_FP8(v3);
        ADD_FP8(v4); ADD_FP8(v5); ADD_FP8(v6); ADD_FP8(v7);
    }
    for (; it + 3 < e; it += 4) {
        int c0 = adj[it + 0], c1 = adj[it + 1], c2 = adj[it + 2], c3 = adj[it + 3];
        uint2 v0 = *(const uint2*)&zb[(size_t)c0 * 128];
        uint2 v1 = *(const uint2*)&zb[(size_t)c1 * 128];
        uint2 v2 = *(const uint2*)&zb[(size_t)c2 * 128];
        uint2 v3 = *(const uint2*)&zb[(size_t)c3 * 128];
        ADD_FP8(v0); ADD_FP8(v1); ADD_FP8(v2); ADD_FP8(v3);
    }
    for (; it + 1 < e; it += 2) {
        int c0 = adj[it + 0], c1 = adj[it + 1];
        uint2 v0 = *(const uint2*)&zb[(size_t)c0 * 128];
        uint2 v1 = *(const uint2*)&zb[(size_t)c1 * 128];
        ADD_FP8(v0); ADD_FP8(v1);
    }
    if (it < e) {
        int c = adj[it];
        uint2 v = *(const uint2*)&zb[(size_t)c * 128];
        ADD_FP8(v);
    }
#undef ADD_FP8

    float* hp = H + (size_t)node * DIM + sl * 8;
    f32x4 h0 = __builtin_nontemporal_load((const f32x4*)hp);
    f32x4 h1 = __builtin_nontemporal_load((const f32x4*)(hp + 4));
    float4 b0 = *(const float4*)&bias[sl * 8];
    float4 b1 = *(const float4*)&bias[sl * 8 + 4];
    float r0 = acc[0] + b0.x, r1 = acc[1] + b0.y, r2 = acc[2] + b0.z, r3 = acc[3] + b0.w;
    float r4 = acc[4] + b1.x, r5 = acc[5] + b1.y, r6 = acc[6] + b1.z, r7 = acc[7] + b1.w;
    h0.x += r0 > 0.f ? r0 : 0.f;  h0.y += r1 > 0.f ? r1 : 0.f;
    h0.z += r2 > 0.f ? r2 : 0.f;  h0.w += r3 > 0.f ? r3 : 0.f;
    h1.x += r4 > 0.f ? r4 : 0.f;  h1.y += r5 > 0.f ? r5 : 0.f;
    h1.z += r6 > 0.f ? r6 : 0.f;  h1.w += r7 > 0.f ? r7 : 0.f;
    __builtin_nontemporal_store(h0, (f32x4*)hp);
    __builtin_nontemporal_store(h1, (f32x4*)(hp + 4));
}

// ---------------------------------------------------------------------------
extern "C" void kernel_launch(void* const* d_in, const int* in_sizes, int n_in,
                              void* d_out, int out_size, void* d_ws, size_t ws_size,
                              hipStream_t stream) {
    const float* x   = (const float*)d_in[0];
    const int*   ei  = (const int*)d_in[1];
    const float* W_t = (const float*)d_in[2];
    const float* b_t = (const float*)d_in[3];
    const float* W0  = (const float*)d_in[4];
    const float* b0  = (const float*)d_in[5];
    const float* W1  = (const float*)d_in[6];
    const float* b1  = (const float*)d_in[7];

    const int* rows = ei;
    const int* cols = ei + N_EDGES;

    float* H = (float*)d_out;   // fp32 h lives here the whole time

    // workspace layout (~20 MB)
    char* w = (char*)d_ws;
    __hip_bfloat16* Z0 = (__hip_bfloat16*)w;  w += (size_t)N_NODES * DIM * 2;
    unsigned char*  Z1 = (unsigned char*)w;   w += (size_t)N_NODES * DIM;      // fp8
    short* WtF = (short*)w;  w += 128 * 128 * 2;
    short* WfF = (short*)w;  w += 128 * 128 * 2;
    short* W1F = (short*)w;  w += 128 * 128 * 2;
    float* btf = (float*)w;  w += 128 * 4;
    int* row_ptr = (int*)w;  w += (N_NODES + 1) * 4;
    int* flagtot = (int*)w;  w += 768 * 4;           // flags | totals
    unsigned int* cnt8w = (unsigned int*)w;  w += (size_t)CHUNKS * LDSW * 4;  // 2.56 MB
    unsigned char* rank8 = (unsigned char*)w;  w += (size_t)N_EDGES;          // 640 KB
    unsigned short* adj  = (unsigned short*)w;  // E u16

    int* flags  = flagtot;
    int* totals = flagtot + 256;

    // D1: weight prep || chunk histograms || zero flags+totals
    prep_hist_zero<<<HIST0 + CHUNKS, 256, 0, stream>>>(W_t, W0, W1, b_t,
                                                       WtF, WfF, W1F, btf, flagtot,
                                                       rows, rank8, cnt8w);

    // D2: single-pass scan -> row_ptr; chunk counts -> prefixes in place
    scan_onepass<<<NB, 256, 0, stream>>>((unsigned char*)cnt8w, flags, totals, row_ptr);

    // D3: dual GEMM (bf16 Z0 out) || atomic-free scatter, NT streaming
    gemm_scatter<<<GEMMB + HEB, 256, 0, stream>>>(x, WtF, WfF, b_t, btf, H, Z0,
                                                  rows, cols, rank8,
                                                  (unsigned char*)cnt8w, row_ptr, adj);

    // D4: layer-0 agg (bf16 gather) + layer-1 GEMM fused, NT on H
    agg0_gemm<<<N_NODES / 16, 256, 0, stream>>>(Z0, row_ptr, adj, b0, W1F, H, Z1);

    // D5: final agg (fp8 gather), NT on H: H += relu(agg(Z1) + b1)
    agg_final<<<(N_NODES + 15) / 16, 256, 0, stream>>>(Z1, row_ptr, adj, b1, H);
}

// Round 10
// 177.761 us; speedup vs baseline: 1.1125x; 1.1125x over previous
//
#include <hip/hip_runtime.h>
#include <hip/hip_bf16.h>

#define N_NODES 40000
#define N_EDGES 640000
#define DIM     128
#define NB      157    // scan blocks (256 threads)
#define GEMMB   625    // gemm blocks (64 rows each)
#define HEB     1250   // scatter blocks (2 edges/thread)
#define CHUNKS  64     // hist chunks (one block each)
#define CHUNK_E 10000  // edges per chunk
#define LDSW    10000  // u32 words packing 40000 u8 counters

#define HIST0   65     // first hist block in D1

typedef __attribute__((ext_vector_type(8))) short short8;
typedef __attribute__((ext_vector_type(4))) float f32x4;
typedef __attribute__((ext_vector_type(2))) float f32x2;

__device__ inline short f2bf(float f) {
    __hip_bfloat16 h = __float2bfloat16(f);
    return *reinterpret_cast<short*>(&h);
}
__device__ inline float bf2f(short u) {
    union { unsigned int i; float f; } x;
    x.i = ((unsigned int)(unsigned short)u) << 16;
    return x.f;
}

// fragment-order index for element (k,n) of a 128x128 W, matching the
// MFMA B-fragment read: lane l reads slot (kb*8+nt)*64 + l as short8.
__device__ inline int fragidx(int k, int n) {
    int kb = k >> 5, kq = (k >> 3) & 3, j = k & 7;
    int nt = n >> 4, nl = n & 15;
    return (((kb * 8 + nt) * 64 + kq * 16 + nl) * 8 + j);
}

// ---------------------------------------------------------------------------
// D1: blocks [0,64) weight prep; block 64 zeros flags+totals;
// blocks [65,129) LDS chunk histograms (hist needs only `rows`).
// ---------------------------------------------------------------------------
__global__ __launch_bounds__(256) void prep_hist_zero(const float* __restrict__ Wt,
                                                      const float* __restrict__ W0,
                                                      const float* __restrict__ W1,
                                                      const float* __restrict__ bt,
                                                      short* __restrict__ WtF,
                                                      short* __restrict__ WfF,
                                                      short* __restrict__ W1F,
                                                      float* __restrict__ btf,
                                                      int* __restrict__ flagtot,
                                                      const int* __restrict__ rows,
                                                      unsigned char* __restrict__ rank8,
                                                      unsigned int* __restrict__ cnt8w) {
    __shared__ unsigned int lcnt[LDSW];   // 40 KB (hist blocks only)
    const int b = blockIdx.x;

    if (b < 64) {
        int gid = b * 256 + threadIdx.x;            // 0..16383
        int k = gid >> 7, n = gid & 127;
        float wf = 0.f;
        for (int kk = 0; kk < 128; ++kk)
            wf += Wt[k * 128 + kk] * W0[kk * 128 + n];
        int fi = fragidx(k, n);
        WtF[fi] = f2bf(Wt[k * 128 + n]);
        W1F[fi] = f2bf(W1[k * 128 + n]);
        WfF[fi] = f2bf(wf);
        if (gid < 128) {
            float s = 0.f;
            for (int kk = 0; kk < 128; ++kk) s += bt[kk] * W0[kk * 128 + n];
            btf[n] = s;
        }
    } else if (b == 64) {
        flagtot[threadIdx.x]       = 0;   // flags
        flagtot[threadIdx.x + 256] = 0;   // totals
    } else {
        // LDS histogram of one 10000-edge chunk: u8 counters packed 4/u32;
        // returning LDS atomicAdd gives rank within chunk-bucket.
        for (int i = threadIdx.x; i < LDSW; i += 256) lcnt[i] = 0u;
        __syncthreads();
        const int base = (b - HIST0) * CHUNK_E;
#pragma unroll
        for (int i = 0; i < 40; ++i) {
            int o = i * 256 + threadIdx.x;
            if (o < CHUNK_E) {
                int e = base + o;
                int r = rows[e];
                unsigned int sh = (unsigned int)(r & 3) * 8u;
                unsigned int old = atomicAdd(&lcnt[r >> 2], 1u << sh);
                rank8[e] = (unsigned char)((old >> sh) & 0xFFu);
            }
        }
        __syncthreads();
        unsigned int* out = cnt8w + (size_t)(b - HIST0) * LDSW;
        for (int i = threadIdx.x; i < LDSW; i += 256) out[i] = lcnt[i];
    }
}

// ---------------------------------------------------------------------------
// D2': scan || dual GEMM fused — ZERO cross-role dependency.
//   blocks [0,157):   single-pass scan. The publish-then-spin involves ONLY
//                     this 157-block clique (all resident: first dispatched).
//                     GEMM blocks never touch flags/totals, so the atomic
//                     traffic on the spin lines is identical to standalone —
//                     this avoids R1's failure mode (thousands of foreign
//                     blocks spinning across a producer gap).
//   blocks [157,782): H = x@Wt + bt (fp32), Z0 = bf16(x@(Wt@W0) + bt@W0);
//                     depends only on D1 outputs.
// ---------------------------------------------------------------------------
__global__ __launch_bounds__(256) void scan_gemm(unsigned char* __restrict__ cnt8,
                                                 int* __restrict__ flags,
                                                 int* __restrict__ totals,
                                                 int* __restrict__ row_ptr,
                                                 const float* __restrict__ A,
                                                 const short* __restrict__ WtF,
                                                 const short* __restrict__ WfF,
                                                 const float* __restrict__ bt,
                                                 const float* __restrict__ btf,
                                                 float* __restrict__ H,
                                                 __hip_bfloat16* __restrict__ Z) {
    __shared__ int sh[256];
    const int blk = blockIdx.x;
    const int t   = threadIdx.x;

    if (blk < NB) {
        // ---------------- scan role ----------------
        const int b = blk;
        const int i = b * 256 + t;

        int deg = 0;
        if (i < N_NODES) {
#pragma unroll 8
            for (int c = 0; c < CHUNKS; ++c) deg += cnt8[(size_t)c * N_NODES + i];
        }

        int val = deg;
        sh[t] = val;
        __syncthreads();
        for (int off = 1; off < 256; off <<= 1) {
            int a = (t >= off) ? sh[t - off] : 0;
            __syncthreads();
            val += a;
            sh[t] = val;
            __syncthreads();
        }
        const int excl  = val - deg;
        const int total = sh[255];

        if (t == 0) {
            atomicExch(&totals[b], total);
            __threadfence();
            atomicExch(&flags[b], 1);
        }

        int v = 0;
        if (t < NB) {
            while (atomicAdd(&flags[t], 0) == 0) { }
            v = atomicAdd(&totals[t], 0);
        }
        __syncthreads();
        int val2 = v;
        sh[t] = val2;
        __syncthreads();
        for (int off = 1; off < 256; off <<= 1) {
            int a = (t >= off) ? sh[t - off] : 0;
            __syncthreads();
            val2 += a;
            sh[t] = val2;
            __syncthreads();
        }
        int blkOff = (b == 0) ? 0 : sh[b - 1];

        if (i < N_NODES) {
            int base = excl + blkOff;
            row_ptr[i] = base;
            int run = 0;
#pragma unroll 8
            for (int c = 0; c < CHUNKS; ++c) {
                int cv = cnt8[(size_t)c * N_NODES + i];
                cnt8[(size_t)c * N_NODES + i] = (unsigned char)run;
                run += cv;
            }
        }
        if (i == 0) row_ptr[N_NODES] = N_EDGES;
        return;
    }

    // ---------------- dual-GEMM role ----------------
    const int wave = t >> 6;
    const int l    = t & 63;
    const int nl   = l & 15;
    const int quad = l >> 4;
    const int wRow = (blk - NB) * 64 + wave * 16;

    f32x4 accH[8], accZ[8];
#pragma unroll
    for (int nt = 0; nt < 8; ++nt) {
        accH[nt] = (f32x4){0.f, 0.f, 0.f, 0.f};
        accZ[nt] = (f32x4){0.f, 0.f, 0.f, 0.f};
    }

#pragma unroll
    for (int kb = 0; kb < 4; ++kb) {
        const float* ap = A + (size_t)(wRow + nl) * 128 + kb * 32 + quad * 8;
        float4 f0 = *(const float4*)ap;
        float4 f1 = *(const float4*)(ap + 4);
        short8 afrag;
        afrag[0] = f2bf(f0.x); afrag[1] = f2bf(f0.y);
        afrag[2] = f2bf(f0.z); afrag[3] = f2bf(f0.w);
        afrag[4] = f2bf(f1.x); afrag[5] = f2bf(f1.y);
        afrag[6] = f2bf(f1.z); afrag[7] = f2bf(f1.w);
#pragma unroll
        for (int nt = 0; nt < 8; ++nt) {
            int off = ((kb * 8 + nt) * 64 + l) * 8;
            short8 bt_frag = *(const short8*)&WtF[off];
            short8 bf_frag = *(const short8*)&WfF[off];
            accH[nt] = __builtin_amdgcn_mfma_f32_16x16x32_bf16(afrag, bt_frag, accH[nt], 0, 0, 0);
            accZ[nt] = __builtin_amdgcn_mfma_f32_16x16x32_bf16(afrag, bf_frag, accZ[nt], 0, 0, 0);
        }
    }

#pragma unroll
    for (int nt = 0; nt < 8; ++nt) {
        int col = nt * 16 + nl;
        float bH = bt[col];
        float bZ = btf[col];
#pragma unroll
        for (int r = 0; r < 4; ++r) {
            int row = wRow + quad * 4 + r;
            H[(size_t)row * 128 + col] = accH[nt][r] + bH;
            *(short*)&Z[(size_t)row * 128 + col] = f2bf(accZ[nt][r] + bZ);
        }
    }
}

// ---------------------------------------------------------------------------
// D3': atomic-free scatter, standalone (pure throughput, no dependencies
// inside the dispatch). pos = row_ptr[r] + pref8[chunk][r] + rank8[e].
// ---------------------------------------------------------------------------
__global__ __launch_bounds__(256) void scatter_plain(const int* __restrict__ rows,
                                                     const int* __restrict__ cols,
                                                     const unsigned char* __restrict__ rank8,
                                                     const unsigned char* __restrict__ pref8,
                                                     const int* __restrict__ row_ptr,
                                                     unsigned short* __restrict__ adj) {
    int gid = blockIdx.x * 256 + threadIdx.x;     // 0..319999
#pragma unroll
    for (int h = 0; h < 2; ++h) {
        int e = gid + h * HEB * 256;
        int r = rows[e];
        int c = e / CHUNK_E;
        int pos = row_ptr[r] + (int)pref8[(size_t)c * N_NODES + r] + (int)rank8[e];
        adj[pos] = (unsigned short)cols[e];
    }
}

// ---------------------------------------------------------------------------
// D4: fused layer-0 agg + layer-1 GEMM — quad-per-node bf16 gather (natural
// order; R5/R6 proved degree-sort loses to locality). 8/4/2/1 unroll ladder
// keeps up to 8 rows in flight per quad. Plain (cached) loads/stores —
// R9 proved NT on H costs ~20 µs (H is producer-consumer across dispatches).
// ---------------------------------------------------------------------------
__global__ __launch_bounds__(256) void agg0_gemm(const __hip_bfloat16* __restrict__ z0,
                                                 const int* __restrict__ row_ptr,
                                                 const unsigned short* __restrict__ adj,
                                                 const float* __restrict__ bias,
                                                 const short* __restrict__ W1F,
                                                 float* __restrict__ H,
                                                 unsigned char* __restrict__ Z1) {
    __shared__ short hs[16][136];   // +8 shorts pad

    const int t    = threadIdx.x;
    const int wave = t >> 6;
    const int l    = t & 63;
    const int quad = l >> 4;
    const int sl   = l & 15;
    const int nodeBase = blockIdx.x * 16;
    const int m    = wave * 4 + quad;      // 0..15, this quad's node slot
    const int node = nodeBase + m;

    const int s = row_ptr[node];
    const int e = row_ptr[node + 1];

    float acc[8];
#pragma unroll
    for (int j = 0; j < 8; ++j) acc[j] = 0.f;

    const __hip_bfloat16* zb = z0 + sl * 8;
    int it = s;
    for (; it + 7 < e; it += 8) {
        int c0 = adj[it + 0], c1 = adj[it + 1], c2 = adj[it + 2], c3 = adj[it + 3];
        int c4 = adj[it + 4], c5 = adj[it + 5], c6 = adj[it + 6], c7 = adj[it + 7];
        short8 v0 = *(const short8*)&zb[(size_t)c0 * DIM];
        short8 v1 = *(const short8*)&zb[(size_t)c1 * DIM];
        short8 v2 = *(const short8*)&zb[(size_t)c2 * DIM];
        short8 v3 = *(const short8*)&zb[(size_t)c3 * DIM];
        short8 v4 = *(const short8*)&zb[(size_t)c4 * DIM];
        short8 v5 = *(const short8*)&zb[(size_t)c5 * DIM];
        short8 v6 = *(const short8*)&zb[(size_t)c6 * DIM];
        short8 v7 = *(const short8*)&zb[(size_t)c7 * DIM];
#pragma unroll
        for (int j = 0; j < 8; ++j)
            acc[j] += ((bf2f(v0[j]) + bf2f(v1[j])) + (bf2f(v2[j]) + bf2f(v3[j]))) +
                      ((bf2f(v4[j]) + bf2f(v5[j])) + (bf2f(v6[j]) + bf2f(v7[j])));
    }
    for (; it + 3 < e; it += 4) {
        int c0 = adj[it + 0], c1 = adj[it + 1], c2 = adj[it + 2], c3 = adj[it + 3];
        short8 v0 = *(const short8*)&zb[(size_t)c0 * DIM];
        short8 v1 = *(const short8*)&zb[(size_t)c1 * DIM];
        short8 v2 = *(const short8*)&zb[(size_t)c2 * DIM];
        short8 v3 = *(const short8*)&zb[(size_t)c3 * DIM];
#pragma unroll
        for (int j = 0; j < 8; ++j)
            acc[j] += (bf2f(v0[j]) + bf2f(v1[j])) + (bf2f(v2[j]) + bf2f(v3[j]));
    }
    for (; it + 1 < e; it += 2) {
        int c0 = adj[it + 0], c1 = adj[it + 1];
        short8 v0 = *(const short8*)&zb[(size_t)c0 * DIM];
        short8 v1 = *(const short8*)&zb[(size_t)c1 * DIM];
#pragma unroll
        for (int j = 0; j < 8; ++j) acc[j] += bf2f(v0[j]) + bf2f(v1[j]);
    }
    if (it < e) {
        int c = adj[it];
        short8 v = *(const short8*)&zb[(size_t)c * DIM];
#pragma unroll
        for (int j = 0; j < 8; ++j) acc[j] += bf2f(v[j]);
    }

    // residual update (each quad owns its node; all 16 lanes write 8 floats)
    {
        float* hp = H + (size_t)node * DIM + sl * 8;
        float4 h0 = *(float4*)hp;
        float4 h1 = *(float4*)(hp + 4);
        float4 b0v = *(const float4*)&bias[sl * 8];
        float4 b1v = *(const float4*)&bias[sl * 8 + 4];
        float r[8];
        r[0] = acc[0] + b0v.x; r[1] = acc[1] + b0v.y; r[2] = acc[2] + b0v.z; r[3] = acc[3] + b0v.w;
        r[4] = acc[4] + b1v.x; r[5] = acc[5] + b1v.y; r[6] = acc[6] + b1v.z; r[7] = acc[7] + b1v.w;
        float hn[8];
        hn[0] = h0.x; hn[1] = h0.y; hn[2] = h0.z; hn[3] = h0.w;
        hn[4] = h1.x; hn[5] = h1.y; hn[6] = h1.z; hn[7] = h1.w;
        short8 o;
#pragma unroll
        for (int j = 0; j < 8; ++j) {
            float rr = r[j] > 0.f ? r[j] : 0.f;
            hn[j] += rr;
            o[j] = f2bf(hn[j]);
        }
        *(float4*)hp       = make_float4(hn[0], hn[1], hn[2], hn[3]);
        *(float4*)(hp + 4) = make_float4(hn[4], hn[5], hn[6], hn[7]);
        *(short8*)&hs[m][sl * 8] = o;
    }
    __syncthreads();

    // phase 2: Z1[16x128] = hs @ W1 ; wave handles cols [wave*32, wave*32+32)
    f32x4 acc2[2];
    acc2[0] = (f32x4){0.f, 0.f, 0.f, 0.f};
    acc2[1] = (f32x4){0.f, 0.f, 0.f, 0.f};
#pragma unroll
    for (int kb = 0; kb < 4; ++kb) {
        short8 afrag = *(const short8*)&hs[sl][kb * 32 + quad * 8];
#pragma unroll
        for (int nt2 = 0; nt2 < 2; ++nt2) {
            int nt = wave * 2 + nt2;
            short8 bfrag = *(const short8*)&W1F[((kb * 8 + nt) * 64 + l) * 8];
            acc2[nt2] = __builtin_amdgcn_mfma_f32_16x16x32_bf16(afrag, bfrag, acc2[nt2], 0, 0, 0);
        }
    }
#pragma unroll
    for (int nt2 = 0; nt2 < 2; ++nt2) {
        int col = (wave * 2 + nt2) * 16 + sl;
#pragma unroll
        for (int r = 0; r < 4; ++r) {
            int row = nodeBase + quad * 4 + r;
            float v = acc2[nt2][r];
            int packed = __builtin_amdgcn_cvt_pk_fp8_f32(v, v, 0, false);
            Z1[(size_t)row * 128 + col] = (unsigned char)(packed & 0xFF);
        }
    }
}

// ---------------------------------------------------------------------------
// D5: final aggregation over fp8 Z1 — quad-per-node gather (16 nodes/block,
// natural order). H[node] += relu(agg(Z1)+b1).
// ---------------------------------------------------------------------------
__global__ __launch_bounds__(256) void agg_final(const unsigned char* __restrict__ z1,
                                                 const int* __restrict__ row_ptr,
                                                 const unsigned short* __restrict__ adj,
                                                 const float* __restrict__ bias,
                                                 float* __restrict__ H) {
    const int t    = threadIdx.x;
    const int wave = t >> 6;
    const int l    = t & 63;
    const int quad = l >> 4;
    const int sl   = l & 15;
    const int node = blockIdx.x * 16 + wave * 4 + quad;
    if (node >= N_NODES) return;

    const int s = row_ptr[node];
    const int e = row_ptr[node + 1];

    float acc[8];
#pragma unroll
    for (int j = 0; j < 8; ++j) acc[j] = 0.f;

#define ADD_FP8(u2)                                                          \
    {                                                                        \
        f32x2 a0 = __builtin_amdgcn_cvt_pk_f32_fp8((u2).x, false);           \
        f32x2 a1 = __builtin_amdgcn_cvt_pk_f32_fp8((u2).x, true);            \
        f32x2 a2 = __builtin_amdgcn_cvt_pk_f32_fp8((u2).y, false);           \
        f32x2 a3 = __builtin_amdgcn_cvt_pk_f32_fp8((u2).y, true);            \
        acc[0] += a0.x; acc[1] += a0.y; acc[2] += a1.x; acc[3] += a1.y;      \
        acc[4] += a2.x; acc[5] += a2.y; acc[6] += a3.x; acc[7] += a3.y;      \
    }

    const unsigned char* zb = z1 + sl * 8;
    int it = s;
    for (; it + 7 < e; it += 8) {
        int c0 = adj[it + 0], c1 = adj[it + 1], c2 = adj[it + 2], c3 = adj[it + 3];
        int c4 = adj[it + 4], c5 = adj[it + 5], c6 = adj[it + 6], c7 = adj[it + 7];
        uint2 v0 = *(const uint2*)&zb[(size_t)c0 * 128];
        uint2 v1 = *(const uint2*)&zb[(size_t)c1 * 128];
        uint2 v2 = *(const uint2*)&zb[(size_t)c2 * 128];
        uint2 v3 = *(const uint2*)&zb[(size_t)c3 * 128];
        uint2 v4 = *(const uint2*)&zb[(size_t)c4 * 128];
        uint2 v5 = *(const uint2*)&zb[(size_t)c5 * 128];
        uint2 v6 = *(const uint2*)&zb[(size_t)c6 * 128];
        uint2 v7 = *(const uint2*)&zb[(size_t)c7 * 128];
        ADD_FP8(v0); ADD_FP8(v1); ADD_FP8(v2); ADD_FP8(v3);
        ADD_FP8(v4); ADD_FP8(v5); ADD_FP8(v6); ADD_FP8(v7);
    }
    for (; it + 3 < e; it += 4) {
        int c0 = adj[it + 0], c1 = adj[it + 1], c2 = adj[it + 2], c3 = adj[it + 3];
        uint2 v0 = *(const uint2*)&zb[(size_t)c0 * 128];
        uint2 v1 = *(const uint2*)&zb[(size_t)c1 * 128];
        uint2 v2 = *(const uint2*)&zb[(size_t)c2 * 128];
        uint2 v3 = *(const uint2*)&zb[(size_t)c3 * 128];
        ADD_FP8(v0); ADD_FP8(v1); ADD_FP8(v2); ADD_FP8(v3);
    }
    for (; it + 1 < e; it += 2) {
        int c0 = adj[it + 0], c1 = adj[it + 1];
        uint2 v0 = *(const uint2*)&zb[(size_t)c0 * 128];
        uint2 v1 = *(const uint2*)&zb[(size_t)c1 * 128];
        ADD_FP8(v0); ADD_FP8(v1);
    }
    if (it < e) {
        int c = adj[it];
        uint2 v = *(const uint2*)&zb[(size_t)c * 128];
        ADD_FP8(v);
    }
#undef ADD_FP8

    float* hp = H + (size_t)node * DIM + sl * 8;
    float4 h0 = *(float4*)hp;
    float4 h1 = *(float4*)(hp + 4);
    float4 b0 = *(const float4*)&bias[sl * 8];
    float4 b1 = *(const float4*)&bias[sl * 8 + 4];
    float r0 = acc[0] + b0.x, r1 = acc[1] + b0.y, r2 = acc[2] + b0.z, r3 = acc[3] + b0.w;
    float r4 = acc[4] + b1.x, r5 = acc[5] + b1.y, r6 = acc[6] + b1.z, r7 = acc[7] + b1.w;
    h0.x += r0 > 0.f ? r0 : 0.f;  h0.y += r1 > 0.f ? r1 : 0.f;
    h0.z += r2 > 0.f ? r2 : 0.f;  h0.w += r3 > 0.f ? r3 : 0.f;
    h1.x += r4 > 0.f ? r4 : 0.f;  h1.y += r5 > 0.f ? r5 : 0.f;
    h1.z += r6 > 0.f ? r6 : 0.f;  h1.w += r7 > 0.f ? r7 : 0.f;
    *(float4*)hp       = h0;
    *(float4*)(hp + 4) = h1;
}

// ---------------------------------------------------------------------------
extern "C" void kernel_launch(void* const* d_in, const int* in_sizes, int n_in,
                              void* d_out, int out_size, void* d_ws, size_t ws_size,
                              hipStream_t stream) {
    const float* x   = (const float*)d_in[0];
    const int*   ei  = (const int*)d_in[1];
    const float* W_t = (const float*)d_in[2];
    const float* b_t = (const float*)d_in[3];
    const float* W0  = (const float*)d_in[4];
    const float* b0  = (const float*)d_in[5];
    const float* W1  = (const float*)d_in[6];
    const float* b1  = (const float*)d_in[7];

    const int* rows = ei;
    const int* cols = ei + N_EDGES;

    float* H = (float*)d_out;   // fp32 h lives here the whole time

    // workspace layout (~20 MB)
    char* w = (char*)d_ws;
    __hip_bfloat16* Z0 = (__hip_bfloat16*)w;  w += (size_t)N_NODES * DIM * 2;
    unsigned char*  Z1 = (unsigned char*)w;   w += (size_t)N_NODES * DIM;      // fp8
    short* WtF = (short*)w;  w += 128 * 128 * 2;
    short* WfF = (short*)w;  w += 128 * 128 * 2;
    short* W1F = (short*)w;  w += 128 * 128 * 2;
    float* btf = (float*)w;  w += 128 * 4;
    int* row_ptr = (int*)w;  w += (N_NODES + 1) * 4;
    int* flagtot = (int*)w;  w += 768 * 4;           // flags | totals
    unsigned int* cnt8w = (unsigned int*)w;  w += (size_t)CHUNKS * LDSW * 4;  // 2.56 MB
    unsigned char* rank8 = (unsigned char*)w;  w += (size_t)N_EDGES;          // 640 KB
    unsigned short* adj  = (unsigned short*)w;  // E u16

    int* flags  = flagtot;
    int* totals = flagtot + 256;

    // D1: weight prep || chunk histograms || zero flags+totals
    prep_hist_zero<<<HIST0 + CHUNKS, 256, 0, stream>>>(W_t, W0, W1, b_t,
                                                       WtF, WfF, W1F, btf, flagtot,
                                                       rows, rank8, cnt8w);

    // D2': scan (hidden under) || dual GEMM — no cross-role dependency
    scan_gemm<<<NB + GEMMB, 256, 0, stream>>>((unsigned char*)cnt8w, flags, totals,
                                              row_ptr, x, WtF, WfF, b_t, btf, H, Z0);

    // D3': atomic-free scatter (standalone, pure throughput)
    scatter_plain<<<HEB, 256, 0, stream>>>(rows, cols, rank8, (unsigned char*)cnt8w,
                                           row_ptr, adj);

    // D4: layer-0 agg (bf16 gather) + layer-1 GEMM fused
    agg0_gemm<<<N_NODES / 16, 256, 0, stream>>>(Z0, row_ptr, adj, b0, W1F, H, Z1);

    // D5: final agg (fp8 gather): H += relu(agg(Z1) + b1)
    agg_final<<<(N_NODES + 15) / 16, 256, 0, stream>>>(Z1, row_ptr, adj, b1, H);
}

// Round 11
// 173.501 us; speedup vs baseline: 1.1398x; 1.0246x over previous
//
#include <hip/hip_runtime.h>
#include <hip/hip_bf16.h>

#define N_NODES 40000
#define N_EDGES 640000
#define DIM     128
#define NB      157    // scan blocks (256 threads)
#define GEMMB   625    // gemm blocks (64 rows each)
#define HEB     1250   // scatter blocks (2 edges/thread)
#define CHUNKS  64     // hist chunks (one block each)
#define CHUNK_E 10000  // edges per chunk
#define LDSW    10000  // u32 words packing 40000 u8 counters

#define HIST0   65     // first hist block in D1

typedef __attribute__((ext_vector_type(8))) short short8;
typedef __attribute__((ext_vector_type(4))) float f32x4;
typedef __attribute__((ext_vector_type(2))) float f32x2;

__device__ inline short f2bf(float f) {
    __hip_bfloat16 h = __float2bfloat16(f);
    return *reinterpret_cast<short*>(&h);
}
__device__ inline float bf2f(short u) {
    union { unsigned int i; float f; } x;
    x.i = ((unsigned int)(unsigned short)u) << 16;
    return x.f;
}

// fragment-order index for element (k,n) of a 128x128 W, matching the
// MFMA B-fragment read: lane l reads slot (kb*8+nt)*64 + l as short8.
__device__ inline int fragidx(int k, int n) {
    int kb = k >> 5, kq = (k >> 3) & 3, j = k & 7;
    int nt = n >> 4, nl = n & 15;
    return (((kb * 8 + nt) * 64 + kq * 16 + nl) * 8 + j);
}

// ---------------------------------------------------------------------------
// D1: blocks [0,64) weight prep; block 64 zeros flags+totals;
// blocks [65,129) LDS chunk histograms (hist needs only `rows`).
// ---------------------------------------------------------------------------
__global__ __launch_bounds__(256) void prep_hist_zero(const float* __restrict__ Wt,
                                                      const float* __restrict__ W0,
                                                      const float* __restrict__ W1,
                                                      const float* __restrict__ bt,
                                                      short* __restrict__ WtF,
                                                      short* __restrict__ WfF,
                                                      short* __restrict__ W1F,
                                                      float* __restrict__ btf,
                                                      int* __restrict__ flagtot,
                                                      const int* __restrict__ rows,
                                                      unsigned char* __restrict__ rank8,
                                                      unsigned int* __restrict__ cnt8w) {
    __shared__ unsigned int lcnt[LDSW];   // 40 KB (hist blocks only)
    const int b = blockIdx.x;

    if (b < 64) {
        int gid = b * 256 + threadIdx.x;            // 0..16383
        int k = gid >> 7, n = gid & 127;
        float wf = 0.f;
        for (int kk = 0; kk < 128; ++kk)
            wf += Wt[k * 128 + kk] * W0[kk * 128 + n];
        int fi = fragidx(k, n);
        WtF[fi] = f2bf(Wt[k * 128 + n]);
        W1F[fi] = f2bf(W1[k * 128 + n]);
        WfF[fi] = f2bf(wf);
        if (gid < 128) {
            float s = 0.f;
            for (int kk = 0; kk < 128; ++kk) s += bt[kk] * W0[kk * 128 + n];
            btf[n] = s;
        }
    } else if (b == 64) {
        flagtot[threadIdx.x]       = 0;   // flags
        flagtot[threadIdx.x + 256] = 0;   // totals
    } else {
        // LDS histogram of one 10000-edge chunk: u8 counters packed 4/u32;
        // returning LDS atomicAdd gives rank within chunk-bucket.
        for (int i = threadIdx.x; i < LDSW; i += 256) lcnt[i] = 0u;
        __syncthreads();
        const int base = (b - HIST0) * CHUNK_E;
#pragma unroll
        for (int i = 0; i < 40; ++i) {
            int o = i * 256 + threadIdx.x;
            if (o < CHUNK_E) {
                int e = base + o;
                int r = rows[e];
                unsigned int sh = (unsigned int)(r & 3) * 8u;
                unsigned int old = atomicAdd(&lcnt[r >> 2], 1u << sh);
                rank8[e] = (unsigned char)((old >> sh) & 0xFFu);
            }
        }
        __syncthreads();
        unsigned int* out = cnt8w + (size_t)(b - HIST0) * LDSW;
        for (int i = threadIdx.x; i < LDSW; i += 256) out[i] = lcnt[i];
    }
}

// ---------------------------------------------------------------------------
// D2: single-pass scan (standalone dispatch — publish-then-spin is only safe
// when these 157 blocks are alone on the machine; R1 proved that).
// ---------------------------------------------------------------------------
__global__ __launch_bounds__(256) void scan_onepass(unsigned char* __restrict__ cnt8,
                                                    int* __restrict__ flags,
                                                    int* __restrict__ totals,
                                                    int* __restrict__ row_ptr) {
    __shared__ int sh[256];
    const int b = blockIdx.x;
    const int t = threadIdx.x;
    const int i = b * 256 + t;

    int deg = 0;
    if (i < N_NODES) {
#pragma unroll 8
        for (int c = 0; c < CHUNKS; ++c) deg += cnt8[(size_t)c * N_NODES + i];
    }

    int val = deg;
    sh[t] = val;
    __syncthreads();
    for (int off = 1; off < 256; off <<= 1) {
        int a = (t >= off) ? sh[t - off] : 0;
        __syncthreads();
        val += a;
        sh[t] = val;
        __syncthreads();
    }
    const int excl  = val - deg;
    const int total = sh[255];

    if (t == 0) {
        atomicExch(&totals[b], total);
        __threadfence();
        atomicExch(&flags[b], 1);
    }

    int v = 0;
    if (t < NB) {
        while (atomicAdd(&flags[t], 0) == 0) { }
        v = atomicAdd(&totals[t], 0);
    }
    __syncthreads();
    int val2 = v;
    sh[t] = val2;
    __syncthreads();
    for (int off = 1; off < 256; off <<= 1) {
        int a = (t >= off) ? sh[t - off] : 0;
        __syncthreads();
        val2 += a;
        sh[t] = val2;
        __syncthreads();
    }
    int blkOff = (b == 0) ? 0 : sh[b - 1];

    if (i < N_NODES) {
        int base = excl + blkOff;
        row_ptr[i] = base;
        int run = 0;
#pragma unroll 8
        for (int c = 0; c < CHUNKS; ++c) {
            int cv = cnt8[(size_t)c * N_NODES + i];
            cnt8[(size_t)c * N_NODES + i] = (unsigned char)run;
            run += cv;
        }
    }
    if (i == 0) row_ptr[N_NODES] = N_EDGES;
}

// ---------------------------------------------------------------------------
// D3: dual GEMM || scatter fused — ZERO intra-dispatch dependency.
// ---------------------------------------------------------------------------
__global__ __launch_bounds__(256) void gemm_scatter(const float* __restrict__ A,
                                                    const short* __restrict__ WtF,
                                                    const short* __restrict__ WfF,
                                                    const float* __restrict__ bt,
                                                    const float* __restrict__ btf,
                                                    float* __restrict__ H,
                                                    __hip_bfloat16* __restrict__ Z,
                                                    const int* __restrict__ rows,
                                                    const int* __restrict__ cols,
                                                    const unsigned char* __restrict__ rank8,
                                                    const unsigned char* __restrict__ pref8,
                                                    const int* __restrict__ row_ptr,
                                                    unsigned short* __restrict__ adj) {
    const int blk = blockIdx.x;
    const int t   = threadIdx.x;

    if (blk < GEMMB) {
        // ---------------- dual-GEMM role ----------------
        const int wave = t >> 6;
        const int l    = t & 63;
        const int nl   = l & 15;
        const int quad = l >> 4;
        const int wRow = blk * 64 + wave * 16;

        f32x4 accH[8], accZ[8];
#pragma unroll
        for (int nt = 0; nt < 8; ++nt) {
            accH[nt] = (f32x4){0.f, 0.f, 0.f, 0.f};
            accZ[nt] = (f32x4){0.f, 0.f, 0.f, 0.f};
        }

#pragma unroll
        for (int kb = 0; kb < 4; ++kb) {
            const float* ap = A + (size_t)(wRow + nl) * 128 + kb * 32 + quad * 8;
            float4 f0 = *(const float4*)ap;
            float4 f1 = *(const float4*)(ap + 4);
            short8 afrag;
            afrag[0] = f2bf(f0.x); afrag[1] = f2bf(f0.y);
            afrag[2] = f2bf(f0.z); afrag[3] = f2bf(f0.w);
            afrag[4] = f2bf(f1.x); afrag[5] = f2bf(f1.y);
            afrag[6] = f2bf(f1.z); afrag[7] = f2bf(f1.w);
#pragma unroll
            for (int nt = 0; nt < 8; ++nt) {
                int off = ((kb * 8 + nt) * 64 + l) * 8;
                short8 bt_frag = *(const short8*)&WtF[off];
                short8 bf_frag = *(const short8*)&WfF[off];
                accH[nt] = __builtin_amdgcn_mfma_f32_16x16x32_bf16(afrag, bt_frag, accH[nt], 0, 0, 0);
                accZ[nt] = __builtin_amdgcn_mfma_f32_16x16x32_bf16(afrag, bf_frag, accZ[nt], 0, 0, 0);
            }
        }

#pragma unroll
        for (int nt = 0; nt < 8; ++nt) {
            int col = nt * 16 + nl;
            float bH = bt[col];
            float bZ = btf[col];
#pragma unroll
            for (int r = 0; r < 4; ++r) {
                int row = wRow + quad * 4 + r;
                H[(size_t)row * 128 + col] = accH[nt][r] + bH;
                *(short*)&Z[(size_t)row * 128 + col] = f2bf(accZ[nt][r] + bZ);
            }
        }
        return;
    }

    // ---------------- scatter role (atomic-free) ----------------
    int gid = (blk - GEMMB) * 256 + t;            // 0..319999
#pragma unroll
    for (int h = 0; h < 2; ++h) {
        int e = gid + h * HEB * 256;
        int r = rows[e];
        int c = e / CHUNK_E;
        int pos = row_ptr[r] + (int)pref8[(size_t)c * N_NODES + r] + (int)rank8[e];
        adj[pos] = (unsigned short)cols[e];
    }
}

// ---------------------------------------------------------------------------
// D4: fused layer-0 agg + layer-1 GEMM — quad-per-node bf16 gather with
// INDEX PRELOAD: lane i of the quad loads adj[s+i], adj[s+16+i], adj[s+32+i]
// (3 loads replace up to 16 scalar index loads), then __shfl broadcasts each
// index from registers. All row loads then issue with no memory dependency
// between them — the adj->row alternation is removed from the critical chain.
// First 16 rows are straight-line unconditional (indices clamped to 0,
// contributions masked to exact +0.0 for k >= deg), preserving the old
// 8/4/2/1 summation order bit-for-bit. shfl sources are always within the
// reading quad and branches are quad-uniform => bpermute-safe.
// ---------------------------------------------------------------------------
__global__ __launch_bounds__(256) void agg0_gemm(const __hip_bfloat16* __restrict__ z0,
                                                 const int* __restrict__ row_ptr,
                                                 const unsigned short* __restrict__ adj,
                                                 const float* __restrict__ bias,
                                                 const short* __restrict__ W1F,
                                                 float* __restrict__ H,
                                                 unsigned char* __restrict__ Z1) {
    __shared__ short hs[16][136];   // +8 shorts pad

    const int t    = threadIdx.x;
    const int wave = t >> 6;
    const int l    = t & 63;
    const int quad = l >> 4;
    const int sl   = l & 15;
    const int qb   = l & 48;               // absolute base lane of this quad
    const int nodeBase = blockIdx.x * 16;
    const int m    = wave * 4 + quad;      // 0..15, this quad's node slot
    const int node = nodeBase + m;

    const int s   = row_ptr[node];
    const int e   = row_ptr[node + 1];
    const int cnt = e - s;

    // lane-parallel index preload (reads <=47 entries past the segment stay
    // inside the workspace arena; values masked out below)
    int A0 = (int)adj[s + sl];
    int A1 = (cnt > 16) ? (int)adj[s + 16 + sl] : 0;
    int A2 = (cnt > 32) ? (int)adj[s + 32 + sl] : 0;

    float acc[8];
#pragma unroll
    for (int j = 0; j < 8; ++j) acc[j] = 0.f;

    const __hip_bfloat16* zb = z0 + sl * 8;

#define GBLK8(AV, LO, KB)                                                     \
    {                                                                         \
        int i0_ = __shfl(AV, qb + LO + 0), i1_ = __shfl(AV, qb + LO + 1);     \
        int i2_ = __shfl(AV, qb + LO + 2), i3_ = __shfl(AV, qb + LO + 3);     \
        int i4_ = __shfl(AV, qb + LO + 4), i5_ = __shfl(AV, qb + LO + 5);     \
        int i6_ = __shfl(AV, qb + LO + 6), i7_ = __shfl(AV, qb + LO + 7);     \
        i0_ = ((KB) + 0 < cnt) ? i0_ : 0;  i1_ = ((KB) + 1 < cnt) ? i1_ : 0;  \
        i2_ = ((KB) + 2 < cnt) ? i2_ : 0;  i3_ = ((KB) + 3 < cnt) ? i3_ : 0;  \
        i4_ = ((KB) + 4 < cnt) ? i4_ : 0;  i5_ = ((KB) + 5 < cnt) ? i5_ : 0;  \
        i6_ = ((KB) + 6 < cnt) ? i6_ : 0;  i7_ = ((KB) + 7 < cnt) ? i7_ : 0;  \
        short8 v0_ = *(const short8*)&zb[(size_t)i0_ * DIM];                  \
        short8 v1_ = *(const short8*)&zb[(size_t)i1_ * DIM];                  \
        short8 v2_ = *(const short8*)&zb[(size_t)i2_ * DIM];                  \
        short8 v3_ = *(const short8*)&zb[(size_t)i3_ * DIM];                  \
        short8 v4_ = *(const short8*)&zb[(size_t)i4_ * DIM];                  \
        short8 v5_ = *(const short8*)&zb[(size_t)i5_ * DIM];                  \
        short8 v6_ = *(const short8*)&zb[(size_t)i6_ * DIM];                  \
        short8 v7_ = *(const short8*)&zb[(size_t)i7_ * DIM];                  \
        _Pragma("unroll")                                                     \
        for (int jj = 0; jj < 8; ++jj) {                                      \
            float t0_ = ((KB) + 0 < cnt) ? bf2f(v0_[jj]) : 0.f;               \
            float t1_ = ((KB) + 1 < cnt) ? bf2f(v1_[jj]) : 0.f;               \
            float t2_ = ((KB) + 2 < cnt) ? bf2f(v2_[jj]) : 0.f;               \
            float t3_ = ((KB) + 3 < cnt) ? bf2f(v3_[jj]) : 0.f;               \
            float t4_ = ((KB) + 4 < cnt) ? bf2f(v4_[jj]) : 0.f;               \
            float t5_ = ((KB) + 5 < cnt) ? bf2f(v5_[jj]) : 0.f;               \
            float t6_ = ((KB) + 6 < cnt) ? bf2f(v6_[jj]) : 0.f;               \
            float t7_ = ((KB) + 7 < cnt) ? bf2f(v7_[jj]) : 0.f;               \
            acc[jj] += ((t0_ + t1_) + (t2_ + t3_)) + ((t4_ + t5_) + (t6_ + t7_)); \
        }                                                                     \
    }

    GBLK8(A0, 0, 0);
    GBLK8(A0, 8, 8);
    if (cnt > 16) GBLK8(A1, 0, 16);
    if (cnt > 24) GBLK8(A1, 8, 24);
    if (cnt > 32) GBLK8(A2, 0, 32);
    if (cnt > 40) GBLK8(A2, 8, 40);
    if (cnt > 48) {                       // essentially never (Poisson(16))
        for (int k = 48; k < cnt; ++k) {
            int c = adj[s + k];
            short8 v = *(const short8*)&zb[(size_t)c * DIM];
#pragma unroll
            for (int j = 0; j < 8; ++j) acc[j] += bf2f(v[j]);
        }
    }
#undef GBLK8

    // residual update (each quad owns its node; all 16 lanes write 8 floats)
    {
        float* hp = H + (size_t)node * DIM + sl * 8;
        float4 h0 = *(float4*)hp;
        float4 h1 = *(float4*)(hp + 4);
        float4 b0v = *(const float4*)&bias[sl * 8];
        float4 b1v = *(const float4*)&bias[sl * 8 + 4];
        float r[8];
        r[0] = acc[0] + b0v.x; r[1] = acc[1] + b0v.y; r[2] = acc[2] + b0v.z; r[3] = acc[3] + b0v.w;
        r[4] = acc[4] + b1v.x; r[5] = acc[5] + b1v.y; r[6] = acc[6] + b1v.z; r[7] = acc[7] + b1v.w;
        float hn[8];
        hn[0] = h0.x; hn[1] = h0.y; hn[2] = h0.z; hn[3] = h0.w;
        hn[4] = h1.x; hn[5] = h1.y; hn[6] = h1.z; hn[7] = h1.w;
        short8 o;
#pragma unroll
        for (int j = 0; j < 8; ++j) {
            float rr = r[j] > 0.f ? r[j] : 0.f;
            hn[j] += rr;
            o[j] = f2bf(hn[j]);
        }
        *(float4*)hp       = make_float4(hn[0], hn[1], hn[2], hn[3]);
        *(float4*)(hp + 4) = make_float4(hn[4], hn[5], hn[6], hn[7]);
        *(short8*)&hs[m][sl * 8] = o;
    }
    __syncthreads();

    // phase 2: Z1[16x128] = hs @ W1 ; wave handles cols [wave*32, wave*32+32)
    f32x4 acc2[2];
    acc2[0] = (f32x4){0.f, 0.f, 0.f, 0.f};
    acc2[1] = (f32x4){0.f, 0.f, 0.f, 0.f};
#pragma unroll
    for (int kb = 0; kb < 4; ++kb) {
        short8 afrag = *(const short8*)&hs[sl][kb * 32 + quad * 8];
#pragma unroll
        for (int nt2 = 0; nt2 < 2; ++nt2) {
            int nt = wave * 2 + nt2;
            short8 bfrag = *(const short8*)&W1F[((kb * 8 + nt) * 64 + l) * 8];
            acc2[nt2] = __builtin_amdgcn_mfma_f32_16x16x32_bf16(afrag, bfrag, acc2[nt2], 0, 0, 0);
        }
    }
#pragma unroll
    for (int nt2 = 0; nt2 < 2; ++nt2) {
        int col = (wave * 2 + nt2) * 16 + sl;
#pragma unroll
        for (int r = 0; r < 4; ++r) {
            int row = nodeBase + quad * 4 + r;
            float v = acc2[nt2][r];
            int packed = __builtin_amdgcn_cvt_pk_fp8_f32(v, v, 0, false);
            Z1[(size_t)row * 128 + col] = (unsigned char)(packed & 0xFF);
        }
    }
}

// ---------------------------------------------------------------------------
// D5: final aggregation over fp8 Z1 — quad-per-node gather with the same
// index-preload + shfl-broadcast structure (sequential adds preserved
// bit-for-bit via masked +0.0). H[node] += relu(agg(Z1)+b1).
// ---------------------------------------------------------------------------
__global__ __launch_bounds__(256) void agg_final(const unsigned char* __restrict__ z1,
                                                 const int* __restrict__ row_ptr,
                                                 const unsigned short* __restrict__ adj,
                                                 const float* __restrict__ bias,
                                                 float* __restrict__ H) {
    const int t    = threadIdx.x;
    const int wave = t >> 6;
    const int l    = t & 63;
    const int quad = l >> 4;
    const int sl   = l & 15;
    const int qb   = l & 48;
    const int node = blockIdx.x * 16 + wave * 4 + quad;
    if (node >= N_NODES) return;

    const int s   = row_ptr[node];
    const int e   = row_ptr[node + 1];
    const int cnt = e - s;

    int A0 = (int)adj[s + sl];
    int A1 = (cnt > 16) ? (int)adj[s + 16 + sl] : 0;
    int A2 = (cnt > 32) ? (int)adj[s + 32 + sl] : 0;

    float acc[8];
#pragma unroll
    for (int j = 0; j < 8; ++j) acc[j] = 0.f;

    const unsigned char* zb = z1 + sl * 8;

#define ADD_FP8M(u2, M)                                                       \
    {                                                                         \
        f32x2 a0_ = __builtin_amdgcn_cvt_pk_f32_fp8((u2).x, false);           \
        f32x2 a1_ = __builtin_amdgcn_cvt_pk_f32_fp8((u2).x, true);            \
        f32x2 a2_ = __builtin_amdgcn_cvt_pk_f32_fp8((u2).y, false);           \
        f32x2 a3_ = __builtin_amdgcn_cvt_pk_f32_fp8((u2).y, true);            \
        acc[0] += (M) ? a0_.x : 0.f;  acc[1] += (M) ? a0_.y : 0.f;            \
        acc[2] += (M) ? a1_.x : 0.f;  acc[3] += (M) ? a1_.y : 0.f;            \
        acc[4] += (M) ? a2_.x : 0.f;  acc[5] += (M) ? a2_.y : 0.f;            \
        acc[6] += (M) ? a3_.x : 0.f;  acc[7] += (M) ? a3_.y : 0.f;            \
    }

#define FBLK8(AV, LO, KB)                                                     \
    {                                                                         \
        int i0_ = __shfl(AV, qb + LO + 0), i1_ = __shfl(AV, qb + LO + 1);     \
        int i2_ = __shfl(AV, qb + LO + 2), i3_ = __shfl(AV, qb + LO + 3);     \
        int i4_ = __shfl(AV, qb + LO + 4), i5_ = __shfl(AV, qb + LO + 5);     \
        int i6_ = __shfl(AV, qb + LO + 6), i7_ = __shfl(AV, qb + LO + 7);     \
        i0_ = ((KB) + 0 < cnt) ? i0_ : 0;  i1_ = ((KB) + 1 < cnt) ? i1_ : 0;  \
        i2_ = ((KB) + 2 < cnt) ? i2_ : 0;  i3_ = ((KB) + 3 < cnt) ? i3_ : 0;  \
        i4_ = ((KB) + 4 < cnt) ? i4_ : 0;  i5_ = ((KB) + 5 < cnt) ? i5_ : 0;  \
        i6_ = ((KB) + 6 < cnt) ? i6_ : 0;  i7_ = ((KB) + 7 < cnt) ? i7_ : 0;  \
        uint2 v0_ = *(const uint2*)&zb[(size_t)i0_ * 128];                    \
        uint2 v1_ = *(const uint2*)&zb[(size_t)i1_ * 128];                    \
        uint2 v2_ = *(const uint2*)&zb[(size_t)i2_ * 128];                    \
        uint2 v3_ = *(const uint2*)&zb[(size_t)i3_ * 128];                    \
        uint2 v4_ = *(const uint2*)&zb[(size_t)i4_ * 128];                    \
        uint2 v5_ = *(const uint2*)&zb[(size_t)i5_ * 128];                    \
        uint2 v6_ = *(const uint2*)&zb[(size_t)i6_ * 128];                    \
        uint2 v7_ = *(const uint2*)&zb[(size_t)i7_ * 128];                    \
        ADD_FP8M(v0_, (KB) + 0 < cnt);  ADD_FP8M(v1_, (KB) + 1 < cnt);        \
        ADD_FP8M(v2_, (KB) + 2 < cnt);  ADD_FP8M(v3_, (KB) + 3 < cnt);        \
        ADD_FP8M(v4_, (KB) + 4 < cnt);  ADD_FP8M(v5_, (KB) + 5 < cnt);        \
        ADD_FP8M(v6_, (KB) + 6 < cnt);  ADD_FP8M(v7_, (KB) + 7 < cnt);        \
    }

    FBLK8(A0, 0, 0);
    FBLK8(A0, 8, 8);
    if (cnt > 16) FBLK8(A1, 0, 16);
    if (cnt > 24) FBLK8(A1, 8, 24);
    if (cnt > 32) FBLK8(A2, 0, 32);
    if (cnt > 40) FBLK8(A2, 8, 40);
    if (cnt > 48) {
        for (int k = 48; k < cnt; ++k) {
            int c = adj[s + k];
            uint2 v = *(const uint2*)&zb[(size_t)c * 128];
            ADD_FP8M(v, true);
        }
    }
#undef FBLK8
#undef ADD_FP8M

    float* hp = H + (size_t)node * DIM + sl * 8;
    float4 h0 = *(float4*)hp;
    float4 h1 = *(float4*)(hp + 4);
    float4 b0 = *(const float4*)&bias[sl * 8];
    float4 b1 = *(const float4*)&bias[sl * 8 + 4];
    float r0 = acc[0] + b0.x, r1 = acc[1] + b0.y, r2 = acc[2] + b0.z, r3 = acc[3] + b0.w;
    float r4 = acc[4] + b1.x, r5 = acc[5] + b1.y, r6 = acc[6] + b1.z, r7 = acc[7] + b1.w;
    h0.x += r0 > 0.f ? r0 : 0.f;  h0.y += r1 > 0.f ? r1 : 0.f;
    h0.z += r2 > 0.f ? r2 : 0.f;  h0.w += r3 > 0.f ? r3 : 0.f;
    h1.x += r4 > 0.f ? r4 : 0.f;  h1.y += r5 > 0.f ? r5 : 0.f;
    h1.z += r6 > 0.f ? r6 : 0.f;  h1.w += r7 > 0.f ? r7 : 0.f;
    *(float4*)hp       = h0;
    *(float4*)(hp + 4) = h1;
}

// ---------------------------------------------------------------------------
extern "C" void kernel_launch(void* const* d_in, const int* in_sizes, int n_in,
                              void* d_out, int out_size, void* d_ws, size_t ws_size,
                              hipStream_t stream) {
    const float* x   = (const float*)d_in[0];
    const int*   ei  = (const int*)d_in[1];
    const float* W_t = (const float*)d_in[2];
    const float* b_t = (const float*)d_in[3];
    const float* W0  = (const float*)d_in[4];
    const float* b0  = (const float*)d_in[5];
    const float* W1  = (const float*)d_in[6];
    const float* b1  = (const float*)d_in[7];

    const int* rows = ei;
    const int* cols = ei + N_EDGES;

    float* H = (float*)d_out;   // fp32 h lives here the whole time

    // workspace layout (~20 MB)
    char* w = (char*)d_ws;
    __hip_bfloat16* Z0 = (__hip_bfloat16*)w;  w += (size_t)N_NODES * DIM * 2;
    unsigned char*  Z1 = (unsigned char*)w;   w += (size_t)N_NODES * DIM;      // fp8
    short* WtF = (short*)w;  w += 128 * 128 * 2;
    short* WfF = (short*)w;  w += 128 * 128 * 2;
    short* W1F = (short*)w;  w += 128 * 128 * 2;
    float* btf = (float*)w;  w += 128 * 4;
    int* row_ptr = (int*)w;  w += (N_NODES + 1) * 4;
    int* flagtot = (int*)w;  w += 768 * 4;           // flags | totals
    unsigned int* cnt8w = (unsigned int*)w;  w += (size_t)CHUNKS * LDSW * 4;  // 2.56 MB
    unsigned char* rank8 = (unsigned char*)w;  w += (size_t)N_EDGES;          // 640 KB
    unsigned short* adj  = (unsigned short*)w;  // E u16 (arena slack follows)

    int* flags  = flagtot;
    int* totals = flagtot + 256;

    // D1: weight prep || chunk histograms || zero flags+totals
    prep_hist_zero<<<HIST0 + CHUNKS, 256, 0, stream>>>(W_t, W0, W1, b_t,
                                                       WtF, WfF, W1F, btf, flagtot,
                                                       rows, rank8, cnt8w);

    // D2: single-pass scan -> row_ptr; chunk counts -> prefixes in place
    scan_onepass<<<NB, 256, 0, stream>>>((unsigned char*)cnt8w, flags, totals, row_ptr);

    // D3: dual GEMM || atomic-free scatter
    gemm_scatter<<<GEMMB + HEB, 256, 0, stream>>>(x, WtF, WfF, b_t, btf, H, Z0,
                                                  rows, cols, rank8,
                                                  (unsigned char*)cnt8w, row_ptr, adj);

    // D4: layer-0 agg (index-preload bf16 gather) + layer-1 GEMM fused
    agg0_gemm<<<N_NODES / 16, 256, 0, stream>>>(Z0, row_ptr, adj, b0, W1F, H, Z1);

    // D5: final agg (index-preload fp8 gather): H += relu(agg(Z1) + b1)
    agg_final<<<(N_NODES + 15) / 16, 256, 0, stream>>>(Z1, row_ptr, adj, b1, H);
}